// Round 1
// baseline (215.347 us; speedup 1.0000x reference)
//
#include <hip/hip_runtime.h>
#include <math.h>

#define TB 8    // BATCH
#define TT 12   // T_IN
#define HV 32   // H_VEL

// ---------- f32 velocity branch: sigmoid( relu(LN(x@W1^T + b1)) @ w2 + b2 ) ----------
__device__ __forceinline__ float vel_branch32(const float x[TT],
    const float* __restrict__ w1, const float* __restrict__ b1,
    const float* __restrict__ g,  const float* __restrict__ bn,
    const float* __restrict__ w2, float b2) {
  float h[HV];
  float s1 = 0.f, s2 = 0.f;
#pragma unroll
  for (int j = 0; j < HV; ++j) {
    float hj = b1[j];
#pragma unroll
    for (int t = 0; t < TT; ++t) hj = fmaf(x[t], w1[j*TT + t], hj);
    h[j] = hj;
    s1 += hj;
    s2 = fmaf(hj, hj, s2);
  }
  float mu  = s1 * (1.f/HV);
  float var = s2 * (1.f/HV) - mu*mu;
  float inv = 1.f / sqrtf(var + 1e-5f);
  float acc = b2;
#pragma unroll
  for (int j = 0; j < HV; ++j) {
    float yl = fmaf((h[j]-mu)*inv, g[j], bn[j]);
    yl = fmaxf(yl, 0.f);
    acc = fmaf(yl, w2[j], acc);
  }
  return 1.f / (1.f + expf(-acc));
}

// ---------- f64 velocity branch (recompute style, no h[] array; cold path) ----------
__device__ __noinline__ double vel_branch64(const float* x,
    const float* __restrict__ w1, const float* __restrict__ b1,
    const float* __restrict__ g,  const float* __restrict__ bn,
    const float* __restrict__ w2, float b2) {
  double s1 = 0.0, s2 = 0.0;
  for (int j = 0; j < HV; ++j) {
    double hj = (double)b1[j];
    for (int t = 0; t < TT; ++t) hj = fma((double)x[t], (double)w1[j*TT+t], hj);
    s1 += hj;
    s2 = fma(hj, hj, s2);
  }
  double mu  = s1 / (double)HV;
  double var = s2 / (double)HV - mu*mu;
  double inv = 1.0 / sqrt(var + 1e-5);
  double acc = (double)b2;
  for (int j = 0; j < HV; ++j) {
    double hj = (double)b1[j];
    for (int t = 0; t < TT; ++t) hj = fma((double)x[t], (double)w1[j*TT+t], hj);
    double yl = (hj - mu) * inv * (double)g[j] + (double)bn[j];
    if (yl < 0.0) yl = 0.0;
    acc = fma(yl, (double)w2[j], acc);
  }
  return 1.0 / (1.0 + exp(-acc));
}

// ---------- K0: zero den+pred, block 0 reduces attention scalars ----------
__global__ void __launch_bounds__(256) k_zero_prep(
    float* __restrict__ den, float* __restrict__ pred, int nb,
    const float* __restrict__ attn_w, const float* __restrict__ ln2_g,
    const float* __restrict__ ln2_b, float* __restrict__ scal) {
  int idx = blockIdx.x * blockDim.x + threadIdx.x;
  for (int i = idx; i < nb; i += gridDim.x * blockDim.x) { den[i] = 0.f; pred[i] = 0.f; }
  if (blockIdx.x == 0) {
    __shared__ float sg[256], sb[256];
    float a = 0.f, b = 0.f;
    if (threadIdx.x < 129) {
      float w = attn_w[threadIdx.x];
      a = w * ln2_g[threadIdx.x];
      b = w * ln2_b[threadIdx.x];
    }
    sg[threadIdx.x] = a; sb[threadIdx.x] = b;
    __syncthreads();
    for (int s = 128; s > 0; s >>= 1) {
      if (threadIdx.x < s) { sg[threadIdx.x] += sg[threadIdx.x+s]; sb[threadIdx.x] += sb[threadIdx.x+s]; }
      __syncthreads();
    }
    if (threadIdx.x == 0) { scal[0] = sg[0]; scal[1] = sb[0]; }
  }
}

// ---------- K1: per-(node,batch) precompute {Sz, Sz2, p_src, p_dst} ----------
__global__ void __launch_bounds__(256) k_node(
    const float* __restrict__ feature, const float* __restrict__ fc_w,
    const float* __restrict__ attn_w,  const float* __restrict__ ln2_g,
    float4* __restrict__ nodepre, int n_nodes) {
  int idx = blockIdx.x * blockDim.x + threadIdx.x;
  int total = n_nodes * TB;
  if (idx >= total) return;
  const float4* f4 = (const float4*)(feature + (size_t)idx * TT);
  float4 fa = f4[0], fb = f4[1], fcv = f4[2];
  float x[TT] = {fa.x,fa.y,fa.z,fa.w, fb.x,fb.y,fb.z,fb.w, fcv.x,fcv.y,fcv.z,fcv.w};
  float q = 0.f, r = 0.f, ps = 0.f, pd = 0.f;
#pragma unroll 8
  for (int i = 0; i < 64; ++i) {
    float z = 0.f;
#pragma unroll
    for (int t = 0; t < TT; ++t) z = fmaf(x[t], fc_w[i*TT + t], z);
    q += z;
    r  = fmaf(z, z, r);
    ps = fmaf(z, attn_w[i]      * ln2_g[i],      ps);
    pd = fmaf(z, attn_w[64 + i] * ln2_g[64 + i], pd);
  }
  nodepre[idx] = make_float4(q, r, ps, pd);
}

// ---------- K2: fused edge pass ----------
__global__ void __launch_bounds__(256) k_edge1(
    const float* __restrict__ upstream, const float* __restrict__ downstream,
    const float* __restrict__ feature,  const float* __restrict__ distance,
    const int* __restrict__ src, const int* __restrict__ dst,
    const float* __restrict__ attn_w, const float* __restrict__ ln2_g,
    const float* __restrict__ v11_w, const float* __restrict__ v11_b,
    const float* __restrict__ ln11_g, const float* __restrict__ ln11_b,
    const float* __restrict__ v12_w, const float* __restrict__ v12_b,
    const float* __restrict__ v21_w, const float* __restrict__ v21_b,
    const float* __restrict__ ln21_g, const float* __restrict__ ln21_b,
    const float* __restrict__ v22_w, const float* __restrict__ v22_b,
    const float* __restrict__ v3_w, const float* __restrict__ v3_b,
    const float* __restrict__ alpha,
    const float4* __restrict__ nodepre, const float* __restrict__ scal,
    float* __restrict__ exbuf, float* __restrict__ pebuf, float* __restrict__ den,
    int n_edges) {
  int idx = blockIdx.x * blockDim.x + threadIdx.x;
  if (idx >= n_edges * TB) return;
  int e = idx >> 3, b = idx & 7;

  // vectorized loads of upstream/downstream rows (48B each, contiguous across threads)
  const float4* u4 = (const float4*)(upstream + (size_t)idx * TT);
  float4 a0 = u4[0], a1 = u4[1], a2 = u4[2];
  float xu_in[TT] = {a0.x,a0.y,a0.z,a0.w, a1.x,a1.y,a1.z,a1.w, a2.x,a2.y,a2.z,a2.w};
  const float4* d4 = (const float4*)(downstream + (size_t)idx * TT);
  float4 c0 = d4[0], c1 = d4[1], c2 = d4[2];
  float xd_in[TT] = {c0.x,c0.y,c0.z,c0.w, c1.x,c1.y,c1.z,c1.w, c2.x,c2.y,c2.z,c2.w};

  // --- velocity (f32) ---
  float xu = vel_branch32(xu_in, v11_w, v11_b, ln11_g, ln11_b, v12_w, v12_b[0]);
  float xd = vel_branch32(xd_in, v21_w, v21_b, ln21_g, ln21_b, v22_w, v22_b[0]);
  float y  = fmaf(xu, v3_w[0], fmaf(xd, v3_w[1], v3_b[0]));
  float v  = log1pf(expf(y));

  float dist = distance[e];
  float tt   = dist / (v + 1e-5f);
  float th   = tt * 0.1f;
  float tif  = rintf(th);

  // --- selective f64 recompute near round() boundaries (chaos control) ---
  if (fabsf(th - tif) < 1e-3f && tt < 120.0f) {
    double xu64 = vel_branch64(xu_in, v11_w, v11_b, ln11_g, ln11_b, v12_w, v12_b[0]);
    double xd64 = vel_branch64(xd_in, v21_w, v21_b, ln21_g, ln21_b, v22_w, v22_b[0]);
    double y64  = xu64*(double)v3_w[0] + xd64*(double)v3_w[1] + (double)v3_b[0];
    double v64  = log1p(exp(y64));
    double tt64 = (double)dist / (v64 + 1e-5);
    v   = (float)v64;
    tt  = (float)tt64;
    tif = (float)rint(tt64 * 0.1);
  }

  int ti = (int)tif;
  ti = ti < 0 ? 0 : (ti > TT ? TT - 1 : ti);
  int n = TT - ti; n = n < 1 ? 1 : n;

  float al = alpha[e];
  float F  = 1.f / fmaf(al, tt, 1.f);
  float om = 1.f - F;

  // --- diffusion-weighted feature dot (pred_edge) ---
  int s = src[e], d = dst[e];
  const float4* f4 = (const float4*)(feature + ((size_t)s * TB + b) * TT);
  float4 f0 = f4[0], f1 = f4[1], f2 = f4[2];
  float feat[TT] = {f0.x,f0.y,f0.z,f0.w, f1.x,f1.y,f1.z,f1.w, f2.x,f2.y,f2.z,f2.w};
  float pe = 0.f, w = F;
#pragma unroll
  for (int t = TT - 1; t >= 0; --t) {
    if (t < n) { pe = fmaf(w, feat[t], pe); w *= om; }
  }

  // --- attention logit via collapsed LN+dot ---
  float4 nps = nodepre[(size_t)s * TB + b];
  float4 npd = nodepre[(size_t)d * TB + b];
  float sum   = nps.x + npd.x + v;
  float sumsq = nps.y + npd.y + v*v;
  float mu  = sum * (1.f/129.f);
  float var = sumsq * (1.f/129.f) - mu*mu;
  float S1  = nps.z + npd.w + v * attn_w[128] * ln2_g[128];
  float aa  = (S1 - mu*scal[0]) / sqrtf(var + 1e-5f) + scal[1];
  float a   = aa >= 0.f ? aa : 0.01f*aa;
  float ex  = expf(a);

  exbuf[idx] = ex;
  pebuf[idx] = pe;
  atomicAdd(&den[s * TB + b], ex);
}

// ---------- K3: normalize + scatter to pred ----------
__global__ void __launch_bounds__(256) k_edge2(
    const int* __restrict__ src, const int* __restrict__ dst,
    const float* __restrict__ exbuf, const float* __restrict__ pebuf,
    const float* __restrict__ den, float* __restrict__ pred, int n_edges) {
  int idx = blockIdx.x * blockDim.x + threadIdx.x;
  if (idx >= n_edges * TB) return;
  int e = idx >> 3, b = idx & 7;
  float score = exbuf[idx] / den[src[e] * TB + b];
  atomicAdd(&pred[dst[e] * TB + b], score * pebuf[idx]);
}

extern "C" void kernel_launch(void* const* d_in, const int* in_sizes, int n_in,
                              void* d_out, int out_size, void* d_ws, size_t ws_size,
                              hipStream_t stream) {
  const float* upstream   = (const float*)d_in[0];
  const float* downstream = (const float*)d_in[1];
  const float* feature    = (const float*)d_in[2];
  const float* distance   = (const float*)d_in[3];
  const int*   src        = (const int*)d_in[4];
  const int*   dst        = (const int*)d_in[5];
  const float* fc_w   = (const float*)d_in[6];
  const float* attn_w = (const float*)d_in[7];
  const float* ln2_g  = (const float*)d_in[8];
  const float* ln2_b  = (const float*)d_in[9];
  const float* v11_w  = (const float*)d_in[10];
  const float* v11_b  = (const float*)d_in[11];
  const float* ln11_g = (const float*)d_in[12];
  const float* ln11_b = (const float*)d_in[13];
  const float* v12_w  = (const float*)d_in[14];
  const float* v12_b  = (const float*)d_in[15];
  const float* v21_w  = (const float*)d_in[16];
  const float* v21_b  = (const float*)d_in[17];
  const float* ln21_g = (const float*)d_in[18];
  const float* ln21_b = (const float*)d_in[19];
  const float* v22_w  = (const float*)d_in[20];
  const float* v22_b  = (const float*)d_in[21];
  const float* v3_w   = (const float*)d_in[22];
  const float* v3_b   = (const float*)d_in[23];
  const float* alpha  = (const float*)d_in[24];

  int E  = in_sizes[4];
  int N  = in_sizes[2] / (TB * TT);
  int NB = N * TB;
  int EB = E * TB;

  float*  ws      = (float*)d_ws;
  float4* nodepre = (float4*)ws;                // 4*NB floats
  float*  exbuf   = ws + 4 * (size_t)NB;        // EB floats
  float*  pebuf   = exbuf + EB;                 // EB floats
  float*  den     = pebuf + EB;                 // NB floats
  float*  scal    = den + NB;                   // 2 floats
  float*  pred    = (float*)d_out;              // NB floats

  int blk = 256;
  k_zero_prep<<<(NB + blk - 1) / blk, blk, 0, stream>>>(den, pred, NB, attn_w, ln2_g, ln2_b, scal);
  k_node<<<(NB + blk - 1) / blk, blk, 0, stream>>>(feature, fc_w, attn_w, ln2_g, nodepre, N);
  k_edge1<<<(EB + blk - 1) / blk, blk, 0, stream>>>(
      upstream, downstream, feature, distance, src, dst,
      attn_w, ln2_g,
      v11_w, v11_b, ln11_g, ln11_b, v12_w, v12_b,
      v21_w, v21_b, ln21_g, ln21_b, v22_w, v22_b,
      v3_w, v3_b, alpha,
      nodepre, scal, exbuf, pebuf, den, E);
  k_edge2<<<(EB + blk - 1) / blk, blk, 0, stream>>>(src, dst, exbuf, pebuf, den, pred, E);
}

// Round 2
// 196.848 us; speedup vs baseline: 1.0940x; 1.0940x over previous
//
#include <hip/hip_runtime.h>
#include <math.h>

#define TB 8    // BATCH
#define TT 12   // T_IN
#define HV 32   // H_VEL

// ---------- f32 velocity branch: sigmoid( relu(LN(x@W1^T + b1)) @ w2 + b2 ) ----------
__device__ __forceinline__ float vel_branch32(const float x[TT],
    const float* __restrict__ w1, const float* __restrict__ b1,
    const float* __restrict__ g,  const float* __restrict__ bn,
    const float* __restrict__ w2, float b2) {
  float h[HV];
  float s1 = 0.f, s2 = 0.f;
#pragma unroll
  for (int j = 0; j < HV; ++j) {
    float hj = b1[j];
#pragma unroll
    for (int t = 0; t < TT; ++t) hj = fmaf(x[t], w1[j*TT + t], hj);
    h[j] = hj;
    s1 += hj;
    s2 = fmaf(hj, hj, s2);
  }
  float mu  = s1 * (1.f/HV);
  float var = s2 * (1.f/HV) - mu*mu;
  float inv = 1.f / sqrtf(var + 1e-5f);
  float acc = b2;
#pragma unroll
  for (int j = 0; j < HV; ++j) {
    float yl = fmaf((h[j]-mu)*inv, g[j], bn[j]);
    yl = fmaxf(yl, 0.f);
    acc = fmaf(yl, w2[j], acc);
  }
  return 1.f / (1.f + __expf(-acc));
}

// ---------- f64 velocity branch (cold path, rare) ----------
__device__ __noinline__ double vel_branch64(const float* x,
    const float* __restrict__ w1, const float* __restrict__ b1,
    const float* __restrict__ g,  const float* __restrict__ bn,
    const float* __restrict__ w2, float b2) {
  double s1 = 0.0, s2 = 0.0;
  for (int j = 0; j < HV; ++j) {
    double hj = (double)b1[j];
    for (int t = 0; t < TT; ++t) hj = fma((double)x[t], (double)w1[j*TT+t], hj);
    s1 += hj;
    s2 = fma(hj, hj, s2);
  }
  double mu  = s1 / (double)HV;
  double var = s2 / (double)HV - mu*mu;
  double inv = 1.0 / sqrt(var + 1e-5);
  double acc = (double)b2;
  for (int j = 0; j < HV; ++j) {
    double hj = (double)b1[j];
    for (int t = 0; t < TT; ++t) hj = fma((double)x[t], (double)w1[j*TT+t], hj);
    double yl = (hj - mu) * inv * (double)g[j] + (double)bn[j];
    if (yl < 0.0) yl = 0.0;
    acc = fma(yl, (double)w2[j], acc);
  }
  return 1.0 / (1.0 + exp(-acc));
}

// ---------- K0: zero den+pred, block 0 reduces attention scalars ----------
__global__ void __launch_bounds__(256) k_zero_prep(
    float* __restrict__ den, float* __restrict__ pred, int nb,
    const float* __restrict__ attn_w, const float* __restrict__ ln2_g,
    const float* __restrict__ ln2_b, float* __restrict__ scal) {
  int idx = blockIdx.x * blockDim.x + threadIdx.x;
  for (int i = idx; i < nb; i += gridDim.x * blockDim.x) { den[i] = 0.f; pred[i] = 0.f; }
  if (blockIdx.x == 0) {
    __shared__ float sg[256], sb[256];
    float a = 0.f, b = 0.f;
    if (threadIdx.x < 129) {
      float w = attn_w[threadIdx.x];
      a = w * ln2_g[threadIdx.x];
      b = w * ln2_b[threadIdx.x];
    }
    sg[threadIdx.x] = a; sb[threadIdx.x] = b;
    __syncthreads();
    for (int s = 128; s > 0; s >>= 1) {
      if (threadIdx.x < s) { sg[threadIdx.x] += sg[threadIdx.x+s]; sb[threadIdx.x] += sb[threadIdx.x+s]; }
      __syncthreads();
    }
    if (threadIdx.x == 0) { scal[0] = sg[0]; scal[1] = sb[0]; }
  }
}

// ---------- K1: per-(node,batch) precompute {Sz, Sz2, p_src, p_dst} ----------
__global__ void __launch_bounds__(256, 2) k_node(
    const float* __restrict__ feature, const float* __restrict__ fc_w,
    const float* __restrict__ attn_w,  const float* __restrict__ ln2_g,
    float4* __restrict__ nodepre, int n_nodes) {
  int idx = blockIdx.x * blockDim.x + threadIdx.x;
  int total = n_nodes * TB;
  if (idx >= total) return;
  const float4* f4 = (const float4*)(feature + (size_t)idx * TT);
  float4 fa = f4[0], fb = f4[1], fcv = f4[2];
  float x[TT] = {fa.x,fa.y,fa.z,fa.w, fb.x,fb.y,fb.z,fb.w, fcv.x,fcv.y,fcv.z,fcv.w};
  float q = 0.f, r = 0.f, ps = 0.f, pd = 0.f;
#pragma unroll 8
  for (int i = 0; i < 64; ++i) {
    float z = 0.f;
#pragma unroll
    for (int t = 0; t < TT; ++t) z = fmaf(x[t], fc_w[i*TT + t], z);
    q += z;
    r  = fmaf(z, z, r);
    ps = fmaf(z, attn_w[i]      * ln2_g[i],      ps);
    pd = fmaf(z, attn_w[64 + i] * ln2_g[64 + i], pd);
  }
  nodepre[idx] = make_float4(q, r, ps, pd);
}

// ---------- K2: fused edge pass ----------
__global__ void __launch_bounds__(256, 2) k_edge1(
    const float* __restrict__ upstream, const float* __restrict__ downstream,
    const float* __restrict__ feature,  const float* __restrict__ distance,
    const int* __restrict__ src, const int* __restrict__ dst,
    const float* __restrict__ attn_w, const float* __restrict__ ln2_g,
    const float* __restrict__ v11_w, const float* __restrict__ v11_b,
    const float* __restrict__ ln11_g, const float* __restrict__ ln11_b,
    const float* __restrict__ v12_w, const float* __restrict__ v12_b,
    const float* __restrict__ v21_w, const float* __restrict__ v21_b,
    const float* __restrict__ ln21_g, const float* __restrict__ ln21_b,
    const float* __restrict__ v22_w, const float* __restrict__ v22_b,
    const float* __restrict__ v3_w, const float* __restrict__ v3_b,
    const float* __restrict__ alpha,
    const float4* __restrict__ nodepre, const float* __restrict__ scal,
    float2* __restrict__ epbuf, float* __restrict__ den,
    int n_edges) {
  int idx = blockIdx.x * blockDim.x + threadIdx.x;
  if (idx >= n_edges * TB) return;
  int e = idx >> 3, b = idx & 7;

  // --- issue all random gathers early (latency hides under MLP compute) ---
  int s = src[e], d = dst[e];
  float dist = distance[e];
  float al   = alpha[e];
  const float4* f4 = (const float4*)(feature + ((size_t)s * TB + b) * TT);
  float4 f0 = f4[0], f1 = f4[1], f2 = f4[2];
  float4 nps = nodepre[(size_t)s * TB + b];
  float4 npd = nodepre[(size_t)d * TB + b];

  // --- upstream branch (xu_in dead after this) ---
  float xu, xd;
  {
    const float4* u4 = (const float4*)(upstream + (size_t)idx * TT);
    float4 a0 = u4[0], a1 = u4[1], a2 = u4[2];
    float xin[TT] = {a0.x,a0.y,a0.z,a0.w, a1.x,a1.y,a1.z,a1.w, a2.x,a2.y,a2.z,a2.w};
    xu = vel_branch32(xin, v11_w, v11_b, ln11_g, ln11_b, v12_w, v12_b[0]);
  }
  {
    const float4* d4 = (const float4*)(downstream + (size_t)idx * TT);
    float4 c0 = d4[0], c1 = d4[1], c2 = d4[2];
    float xin[TT] = {c0.x,c0.y,c0.z,c0.w, c1.x,c1.y,c1.z,c1.w, c2.x,c2.y,c2.z,c2.w};
    xd = vel_branch32(xin, v21_w, v21_b, ln21_g, ln21_b, v22_w, v22_b[0]);
  }
  float y  = fmaf(xu, v3_w[0], fmaf(xd, v3_w[1], v3_b[0]));
  float v  = log1pf(expf(y));

  float tt   = dist / (v + 1e-5f);
  float th   = tt * 0.1f;
  float tif  = rintf(th);

  // --- selective f64 recompute near round() boundaries (chaos control) ---
  if (fabsf(th - tif) < 1e-3f && tt < 120.0f) {
    const float4* u4 = (const float4*)(upstream + (size_t)idx * TT);
    float4 a0 = u4[0], a1 = u4[1], a2 = u4[2];
    float xiu[TT] = {a0.x,a0.y,a0.z,a0.w, a1.x,a1.y,a1.z,a1.w, a2.x,a2.y,a2.z,a2.w};
    const float4* d4 = (const float4*)(downstream + (size_t)idx * TT);
    float4 c0 = d4[0], c1 = d4[1], c2 = d4[2];
    float xid[TT] = {c0.x,c0.y,c0.z,c0.w, c1.x,c1.y,c1.z,c1.w, c2.x,c2.y,c2.z,c2.w};
    double xu64 = vel_branch64(xiu, v11_w, v11_b, ln11_g, ln11_b, v12_w, v12_b[0]);
    double xd64 = vel_branch64(xid, v21_w, v21_b, ln21_g, ln21_b, v22_w, v22_b[0]);
    double y64  = xu64*(double)v3_w[0] + xd64*(double)v3_w[1] + (double)v3_b[0];
    double v64  = log1p(exp(y64));
    double tt64 = (double)dist / (v64 + 1e-5);
    v   = (float)v64;
    tt  = (float)tt64;
    tif = (float)rint(tt64 * 0.1);
  }

  int ti = (int)tif;
  ti = ti < 0 ? 0 : (ti > TT ? TT - 1 : ti);
  int n = TT - ti; n = n < 1 ? 1 : n;

  float F  = 1.f / fmaf(al, tt, 1.f);
  float om = 1.f - F;

  // --- diffusion-weighted feature dot (pred_edge) ---
  float feat[TT] = {f0.x,f0.y,f0.z,f0.w, f1.x,f1.y,f1.z,f1.w, f2.x,f2.y,f2.z,f2.w};
  float pe = 0.f, w = F;
#pragma unroll
  for (int t = TT - 1; t >= 0; --t) {
    if (t < n) { pe = fmaf(w, feat[t], pe); w *= om; }
  }

  // --- attention logit via collapsed LN+dot ---
  float sum   = nps.x + npd.x + v;
  float sumsq = nps.y + npd.y + v*v;
  float mu  = sum * (1.f/129.f);
  float var = sumsq * (1.f/129.f) - mu*mu;
  float S1  = nps.z + npd.w + v * attn_w[128] * ln2_g[128];
  float aa  = (S1 - mu*scal[0]) / sqrtf(var + 1e-5f) + scal[1];
  float a   = aa >= 0.f ? aa : 0.01f*aa;
  float ex  = __expf(a);

  epbuf[idx] = make_float2(ex, pe);
  atomicAdd(&den[s * TB + b], ex);
}

// ---------- K3: normalize + scatter to pred ----------
__global__ void __launch_bounds__(256) k_edge2(
    const int* __restrict__ src, const int* __restrict__ dst,
    const float2* __restrict__ epbuf,
    const float* __restrict__ den, float* __restrict__ pred, int n_edges) {
  int idx = blockIdx.x * blockDim.x + threadIdx.x;
  if (idx >= n_edges * TB) return;
  int e = idx >> 3, b = idx & 7;
  float2 ep = epbuf[idx];
  float score = ep.x / den[src[e] * TB + b];
  atomicAdd(&pred[dst[e] * TB + b], score * ep.y);
}

extern "C" void kernel_launch(void* const* d_in, const int* in_sizes, int n_in,
                              void* d_out, int out_size, void* d_ws, size_t ws_size,
                              hipStream_t stream) {
  const float* upstream   = (const float*)d_in[0];
  const float* downstream = (const float*)d_in[1];
  const float* feature    = (const float*)d_in[2];
  const float* distance   = (const float*)d_in[3];
  const int*   src        = (const int*)d_in[4];
  const int*   dst        = (const int*)d_in[5];
  const float* fc_w   = (const float*)d_in[6];
  const float* attn_w = (const float*)d_in[7];
  const float* ln2_g  = (const float*)d_in[8];
  const float* ln2_b  = (const float*)d_in[9];
  const float* v11_w  = (const float*)d_in[10];
  const float* v11_b  = (const float*)d_in[11];
  const float* ln11_g = (const float*)d_in[12];
  const float* ln11_b = (const float*)d_in[13];
  const float* v12_w  = (const float*)d_in[14];
  const float* v12_b  = (const float*)d_in[15];
  const float* v21_w  = (const float*)d_in[16];
  const float* v21_b  = (const float*)d_in[17];
  const float* ln21_g = (const float*)d_in[18];
  const float* ln21_b = (const float*)d_in[19];
  const float* v22_w  = (const float*)d_in[20];
  const float* v22_b  = (const float*)d_in[21];
  const float* v3_w   = (const float*)d_in[22];
  const float* v3_b   = (const float*)d_in[23];
  const float* alpha  = (const float*)d_in[24];

  int E  = in_sizes[4];
  int N  = in_sizes[2] / (TB * TT);
  int NB = N * TB;
  int EB = E * TB;

  float*  ws      = (float*)d_ws;
  float4* nodepre = (float4*)ws;                 // 4*NB floats
  float2* epbuf   = (float2*)(ws + 4 * (size_t)NB); // 2*EB floats
  float*  den     = ws + 4 * (size_t)NB + 2 * (size_t)EB; // NB floats
  float*  scal    = den + NB;                    // 2 floats
  float*  pred    = (float*)d_out;               // NB floats

  int blk = 256;
  k_zero_prep<<<(NB + blk - 1) / blk, blk, 0, stream>>>(den, pred, NB, attn_w, ln2_g, ln2_b, scal);
  k_node<<<(NB + blk - 1) / blk, blk, 0, stream>>>(feature, fc_w, attn_w, ln2_g, nodepre, N);
  k_edge1<<<(EB + blk - 1) / blk, blk, 0, stream>>>(
      upstream, downstream, feature, distance, src, dst,
      attn_w, ln2_g,
      v11_w, v11_b, ln11_g, ln11_b, v12_w, v12_b,
      v21_w, v21_b, ln21_g, ln21_b, v22_w, v22_b,
      v3_w, v3_b, alpha,
      nodepre, scal, epbuf, den, E);
  k_edge2<<<(EB + blk - 1) / blk, blk, 0, stream>>>(src, dst, epbuf, den, pred, E);
}